// Round 1
// baseline (10723.090 us; speedup 1.0000x reference)
//
#include <hip/hip_runtime.h>
#include <math.h>

// Problem constants (reference: BS=32, N=M=1024, eps=0.1, 200 iters)
#define BS    32
#define N     1024
#define M     1024
#define ITERS 200

// Decomposition: each batch's 1024x1024 G is split row-wise across WPB
// workgroups. 32 batches * 16 WGs = 512 blocks of 256 threads = 2 blocks/CU,
// so while one WG spins at the inter-WG barrier its CU keeps computing the
// co-resident WG.
#define WPB   16                  // workgroups per batch
#define ROWS  (N / WPB)           // 64 rows per WG
#define T     256                 // threads per WG (4 waves)
#define NWAVES (T / 64)
#define RPW   (ROWS / NWAVES)     // 16 rows per wave

// ws layout: [0,4096) = 32 per-batch barrier counters padded to 128B;
//            [4096, 4096 + 2*BS*WPB*M*4) = double-buffered column partials.
#define CNT_BYTES 4096
#define PARTIALS_FLOATS ((size_t)2 * BS * WPB * M)

__global__ __launch_bounds__(T) void sinkhorn_persistent(
    const float* __restrict__ C,
    float* __restrict__ G,          // d_out: holds G, overwritten with Gamma*n
    float* __restrict__ partials,   // [2][BS][WPB][M]
    unsigned* __restrict__ cnt)     // [BS] stride 32 uints (128B)
{
    const int wg   = blockIdx.x;
    const int b    = wg / WPB;      // batch
    const int k    = wg % WPB;      // row-slice within batch
    const int tid  = threadIdx.x;
    const int lane = tid & 63;
    const int wave = tid >> 6;

    const size_t slice = (size_t)b * N * M + (size_t)k * ROWS * M;
    const float* Cs = C + slice;
    float*       Gs = G + slice;

    __shared__ float v_lds[M];      // full v (1024 floats)
    __shared__ float u_lds[ROWS];   // this WG's u slice

    // ---- one-time: G = exp(-C/eps) for our slice (eps=0.1 -> *-10) ----
    {
        const float4* c4 = (const float4*)Cs;
        float4*       g4 = (float4*)Gs;
        const int nv4 = ROWS * M / 4;   // 16384
        for (int i = tid; i < nv4; i += T) {
            float4 c = c4[i];
            float4 g;
            g.x = expf(-10.0f * c.x);
            g.y = expf(-10.0f * c.y);
            g.z = expf(-10.0f * c.z);
            g.w = expf(-10.0f * c.w);
            g4[i] = g;
        }
    }
    for (int j = tid; j < M; j += T) v_lds[j] = 1.0f / (float)M;
    __syncthreads();

    const float MU = 1.0f / (float)N;
    const float NU = 1.0f / (float)M;
    unsigned* mycnt = cnt + b * 32;

    for (int t = 0; t < ITERS; ++t) {
        // ---- row sweep: u[i] = MU / sum_j G[i][j]*v[j]  (own rows only) ----
        #pragma unroll 1
        for (int rr = 0; rr < RPW; ++rr) {
            const int row = wave * RPW + rr;
            const float4* rp = (const float4*)(Gs + (size_t)row * M);
            const float4* vp = (const float4*)v_lds;
            float acc = 0.0f;
            #pragma unroll
            for (int c = 0; c < 4; ++c) {
                float4 g  = rp[lane + 64 * c];
                float4 vv = vp[lane + 64 * c];
                acc += g.x * vv.x;
                acc += g.y * vv.y;
                acc += g.z * vv.z;
                acc += g.w * vv.w;
            }
            #pragma unroll
            for (int off = 32; off > 0; off >>= 1)
                acc += __shfl_xor(acc, off, 64);
            if (lane == 0) u_lds[row] = MU / acc;
        }
        __syncthreads();

        // ---- column sweep over own rows: partial c[j] = sum_i u[i]*G[i][j]
        // thread owns float2 column-pairs (index tid) and (tid+T).
        float2 a0 = make_float2(0.0f, 0.0f);
        float2 a1 = make_float2(0.0f, 0.0f);
        const float2* gp = (const float2*)Gs;
        #pragma unroll 8
        for (int i = 0; i < ROWS; ++i) {
            const float ui = u_lds[i];
            float2 ga = gp[(size_t)i * (M / 2) + tid];
            float2 gb = gp[(size_t)i * (M / 2) + tid + T];
            a0.x += ui * ga.x; a0.y += ui * ga.y;
            a1.x += ui * gb.x; a1.y += ui * gb.y;
        }
        {
            float2* p2 = (float2*)(partials +
                ((size_t)(t & 1) * BS + b) * ((size_t)WPB * M) + (size_t)k * M);
            p2[tid]     = a0;
            p2[tid + T] = a1;
        }

        // ---- 16-way inter-WG barrier for this batch ----
        __syncthreads();
        if (tid == 0) {
            __hip_atomic_fetch_add(mycnt, 1u, __ATOMIC_RELEASE,
                                   __HIP_MEMORY_SCOPE_AGENT);
            const unsigned target = (unsigned)(WPB) * (unsigned)(t + 1);
            while (__hip_atomic_load(mycnt, __ATOMIC_ACQUIRE,
                                     __HIP_MEMORY_SCOPE_AGENT) < target) {
                __builtin_amdgcn_s_sleep(1);
            }
        }
        __syncthreads();

        // ---- v[j] = NU / sum_p partial[p][j]  (fixed order: deterministic)
        {
            const float2* pall = (const float2*)(partials +
                ((size_t)(t & 1) * BS + b) * ((size_t)WPB * M));
            float2 s0 = make_float2(0.0f, 0.0f);
            float2 s1 = make_float2(0.0f, 0.0f);
            #pragma unroll
            for (int p = 0; p < WPB; ++p) {
                float2 pa = pall[(size_t)p * (M / 2) + tid];
                float2 pb = pall[(size_t)p * (M / 2) + tid + T];
                s0.x += pa.x; s0.y += pa.y;
                s1.x += pb.x; s1.y += pb.y;
            }
            float2* v2 = (float2*)v_lds;
            v2[tid]     = make_float2(NU / s0.x, NU / s0.y);
            v2[tid + T] = make_float2(NU / s1.x, NU / s1.y);
        }
        __syncthreads();
    }

    // ---- Gamma*n = u * G * v * N, in place over our slice ----
    #pragma unroll 1
    for (int rr = 0; rr < RPW; ++rr) {
        const int row = wave * RPW + rr;
        const float un = u_lds[row] * (float)N;
        float4* rp = (float4*)(Gs + (size_t)row * M);
        const float4* vp = (const float4*)v_lds;
        #pragma unroll
        for (int c = 0; c < 4; ++c) {
            float4 g  = rp[lane + 64 * c];
            float4 vv = vp[lane + 64 * c];
            g.x *= un * vv.x;
            g.y *= un * vv.y;
            g.z *= un * vv.z;
            g.w *= un * vv.w;
            rp[lane + 64 * c] = g;
        }
    }
}

extern "C" void kernel_launch(void* const* d_in, const int* in_sizes, int n_in,
                              void* d_out, int out_size, void* d_ws, size_t ws_size,
                              hipStream_t stream) {
    (void)in_sizes; (void)n_in; (void)out_size;

    const float* C = (const float*)d_in[0];
    float* G = (float*)d_out;                         // 32*1024*1024 fp32
    unsigned* cnt = (unsigned*)d_ws;
    float* partials = (float*)((char*)d_ws + CNT_BYTES);

    const size_t needed = CNT_BYTES + PARTIALS_FLOATS * sizeof(float);
    if (ws_size < needed) return;   // fail loudly (output stays poisoned)

    // Re-zero barrier counters every launch (graph replay safe, deterministic).
    hipMemsetAsync(d_ws, 0, CNT_BYTES, stream);

    sinkhorn_persistent<<<dim3(BS * WPB), dim3(T), 0, stream>>>(C, G, partials, cnt);
}

// Round 2
// 2897.440 us; speedup vs baseline: 3.7009x; 3.7009x over previous
//
#include <hip/hip_runtime.h>
#include <math.h>

// Problem constants (reference: BS=32, N=M=1024, eps=0.1, 200 iters)
#define BS    32
#define N     1024
#define M     1024
#define ITERS 200

// Each batch's G split row-wise across WPB workgroups.
// 32*16 = 512 blocks x 256 thr = 2 blocks/CU (spinning WG's CU stays busy).
#define WPB   16
#define ROWS  (N / WPB)           // 64 rows per WG
#define T     256                 // 4 waves
#define NWAVES (T / 64)
#define RPW   (ROWS / NWAVES)     // 16 rows per wave

#define CNT_BYTES 4096
#define PARTIALS_FLOATS ((size_t)2 * BS * WPB * M)

__global__ __launch_bounds__(T) void sinkhorn_fused(
    const float* __restrict__ C,
    float* __restrict__ G,          // d_out: G, overwritten with Gamma*n
    float* __restrict__ partials,   // [2][BS][WPB][M]
    unsigned* __restrict__ cnt)     // [BS] stride-32 uints
{
    const int wg   = blockIdx.x;
    const int b    = wg / WPB;
    const int k    = wg % WPB;
    const int tid  = threadIdx.x;
    const int lane = tid & 63;
    const int wave = tid >> 6;

    const size_t slice = (size_t)b * N * M + (size_t)k * ROWS * M;
    const float* Cs = C + slice;
    float*       Gs = G + slice;

    __shared__ float v_lds[M];            // 4 KB
    __shared__ float u_lds[ROWS];         // 256 B
    __shared__ float part[NWAVES][M];     // 16 KB: per-wave column partials
    __shared__ int   sameflag;

    // ---- one-time: G = exp(-C/eps) (eps=0.1 -> *-10) ----
    {
        const float4* c4 = (const float4*)Cs;
        float4*       g4 = (float4*)Gs;
        for (int i = tid; i < ROWS * M / 4; i += T) {
            float4 c = c4[i];
            float4 g;
            g.x = expf(-10.0f * c.x);
            g.y = expf(-10.0f * c.y);
            g.z = expf(-10.0f * c.z);
            g.w = expf(-10.0f * c.w);
            g4[i] = g;
        }
    }
    ((float4*)v_lds)[tid] = make_float4(1.0f/M, 1.0f/M, 1.0f/M, 1.0f/M);
    __syncthreads();

    const float MU = 1.0f / (float)N;
    const float NU = 1.0f / (float)M;
    unsigned* mycnt = cnt + b * 32;
    const float4* v4 = (const float4*)v_lds;

    // v cached in registers for the row sweep (lane's 16 columns)
    float4 vr0 = v4[lane], vr1 = v4[lane + 64],
           vr2 = v4[lane + 128], vr3 = v4[lane + 192];
    // per-thread copy of its v-group (group index = tid) for convergence check
    float4 vold = make_float4(1.0f/M, 1.0f/M, 1.0f/M, 1.0f/M);

    for (int t = 0; t < ITERS; ++t) {
        // ---- fused sweep: one pass over our 64 rows of G ----
        // u[i] = MU / (G[i].v)  then  colacc[j] += u[i]*G[i][j]  (row in regs)
        float4 ca0 = make_float4(0,0,0,0), ca1 = make_float4(0,0,0,0),
               ca2 = make_float4(0,0,0,0), ca3 = make_float4(0,0,0,0);
        #pragma unroll 2
        for (int rr = 0; rr < RPW; ++rr) {
            const int row = wave * RPW + rr;
            const float4* rp = (const float4*)(Gs + (size_t)row * M);
            float4 g0 = rp[lane], g1 = rp[lane + 64],
                   g2 = rp[lane + 128], g3 = rp[lane + 192];
            float dot = g0.x*vr0.x + g0.y*vr0.y + g0.z*vr0.z + g0.w*vr0.w
                      + g1.x*vr1.x + g1.y*vr1.y + g1.z*vr1.z + g1.w*vr1.w
                      + g2.x*vr2.x + g2.y*vr2.y + g2.z*vr2.z + g2.w*vr2.w
                      + g3.x*vr3.x + g3.y*vr3.y + g3.z*vr3.z + g3.w*vr3.w;
            #pragma unroll
            for (int off = 32; off > 0; off >>= 1)
                dot += __shfl_xor(dot, off, 64);
            const float ui = MU / dot;
            if (lane == 0) u_lds[row] = ui;
            ca0.x += ui*g0.x; ca0.y += ui*g0.y; ca0.z += ui*g0.z; ca0.w += ui*g0.w;
            ca1.x += ui*g1.x; ca1.y += ui*g1.y; ca1.z += ui*g1.z; ca1.w += ui*g1.w;
            ca2.x += ui*g2.x; ca2.y += ui*g2.y; ca2.z += ui*g2.z; ca2.w += ui*g2.w;
            ca3.x += ui*g3.x; ca3.y += ui*g3.y; ca3.z += ui*g3.z; ca3.w += ui*g3.w;
        }
        // wave's column partials -> LDS
        {
            float4* pw = (float4*)part[wave];
            pw[lane]       = ca0;
            pw[lane + 64]  = ca1;
            pw[lane + 128] = ca2;
            pw[lane + 192] = ca3;
        }
        __syncthreads();
        // combine 4 waves (thread tid owns column-group tid), write WG partial
        {
            if (tid == 0) sameflag = 1;   // reset; read only after 2 more syncs
            const float4* p0 = (const float4*)part[0];
            const float4* p1 = (const float4*)part[1];
            const float4* p2 = (const float4*)part[2];
            const float4* p3 = (const float4*)part[3];
            float4 s = p0[tid];
            float4 q1 = p1[tid], q2 = p2[tid], q3 = p3[tid];
            s.x += q1.x; s.y += q1.y; s.z += q1.z; s.w += q1.w;
            s.x += q2.x; s.y += q2.y; s.z += q2.z; s.w += q2.w;
            s.x += q3.x; s.y += q3.y; s.z += q3.z; s.w += q3.w;
            float4* pg = (float4*)(partials +
                ((size_t)(t & 1) * BS + b) * ((size_t)WPB * M) + (size_t)k * M);
            pg[tid] = s;
        }
        __syncthreads();
        // ---- 16-way inter-WG barrier for this batch ----
        if (tid == 0) {
            __hip_atomic_fetch_add(mycnt, 1u, __ATOMIC_RELEASE,
                                   __HIP_MEMORY_SCOPE_AGENT);
            const unsigned target = (unsigned)WPB * (unsigned)(t + 1);
            while (__hip_atomic_load(mycnt, __ATOMIC_ACQUIRE,
                                     __HIP_MEMORY_SCOPE_AGENT) < target) {
                __builtin_amdgcn_s_sleep(1);
            }
        }
        __syncthreads();
        // ---- v = NU / sum_p partial[p]  (fixed order -> bitwise identical
        //      across the batch's 16 WGs -> uniform convergence decision) ----
        {
            const float4* pall = (const float4*)(partials +
                ((size_t)(t & 1) * BS + b) * ((size_t)WPB * M));
            float4 s = pall[tid];
            #pragma unroll
            for (int p = 1; p < WPB; ++p) {
                float4 q = pall[(size_t)p * (M / 4) + tid];
                s.x += q.x; s.y += q.y; s.z += q.z; s.w += q.w;
            }
            float4 vnew = make_float4(NU / s.x, NU / s.y, NU / s.z, NU / s.w);
            bool eq = (__float_as_uint(vnew.x) == __float_as_uint(vold.x)) &&
                      (__float_as_uint(vnew.y) == __float_as_uint(vold.y)) &&
                      (__float_as_uint(vnew.z) == __float_as_uint(vold.z)) &&
                      (__float_as_uint(vnew.w) == __float_as_uint(vold.w));
            vold = vnew;
            ((float4*)v_lds)[tid] = vnew;
            if (!eq) sameflag = 0;
        }
        __syncthreads();
        const bool converged = (sameflag != 0);
        vr0 = v4[lane]; vr1 = v4[lane + 64];
        vr2 = v4[lane + 128]; vr3 = v4[lane + 192];
        // Bitwise fixed point: every remaining iteration would reproduce
        // u,v exactly -> breaking now is bit-identical to running all 200.
        if (converged) break;
    }

    // ---- Gamma*n = u * G * v * N over our slice ----
    #pragma unroll 1
    for (int rr = 0; rr < RPW; ++rr) {
        const int row = wave * RPW + rr;
        const float un = u_lds[row] * (float)N;
        float4* rp = (float4*)(Gs + (size_t)row * M);
        float4 g0 = rp[lane], g1 = rp[lane + 64],
               g2 = rp[lane + 128], g3 = rp[lane + 192];
        g0.x *= un * vr0.x; g0.y *= un * vr0.y; g0.z *= un * vr0.z; g0.w *= un * vr0.w;
        g1.x *= un * vr1.x; g1.y *= un * vr1.y; g1.z *= un * vr1.z; g1.w *= un * vr1.w;
        g2.x *= un * vr2.x; g2.y *= un * vr2.y; g2.z *= un * vr2.z; g2.w *= un * vr2.w;
        g3.x *= un * vr3.x; g3.y *= un * vr3.y; g3.z *= un * vr3.z; g3.w *= un * vr3.w;
        rp[lane]       = g0;
        rp[lane + 64]  = g1;
        rp[lane + 128] = g2;
        rp[lane + 192] = g3;
    }
}

extern "C" void kernel_launch(void* const* d_in, const int* in_sizes, int n_in,
                              void* d_out, int out_size, void* d_ws, size_t ws_size,
                              hipStream_t stream) {
    (void)in_sizes; (void)n_in; (void)out_size;

    const float* C = (const float*)d_in[0];
    float* G = (float*)d_out;
    unsigned* cnt = (unsigned*)d_ws;
    float* partials = (float*)((char*)d_ws + CNT_BYTES);

    const size_t needed = CNT_BYTES + PARTIALS_FLOATS * sizeof(float);
    if (ws_size < needed) return;

    hipMemsetAsync(d_ws, 0, CNT_BYTES, stream);

    sinkhorn_fused<<<dim3(BS * WPB), dim3(T), 0, stream>>>(C, G, partials, cnt);
}